// Round 24
// baseline (212.118 us; speedup 1.0000x reference)
//
#include <hip/hip_runtime.h>
#include <stdint.h>

// Shapes (fixed): B=4, S=2048, D=1024, H=16, DH=64
#define NB 4
#define NS 2048
#define ND 1024
#define NH 16
#define NDH 64

typedef __attribute__((ext_vector_type(8))) short bf16x8;
typedef __attribute__((ext_vector_type(4))) float f32x4;
typedef __attribute__((ext_vector_type(2))) unsigned int u32x2;

#define MFMA16(a, b, c) __builtin_amdgcn_mfma_f32_16x16x32_bf16((a), (b), (c), 0, 0, 0)

__device__ __forceinline__ uint16_t f2bf(float f) {
  uint32_t u = __builtin_bit_cast(uint32_t, f);
  return (uint16_t)((u + 0x7FFFu + ((u >> 16) & 1u)) >> 16);
}

// truncating bf16x2 pack (P values; downward bias cancels in o/rs ratio).
__device__ __forceinline__ uint32_t pk2(float lo, float hi) {
  return (__builtin_bit_cast(uint32_t, hi) & 0xFFFF0000u) |
         (__builtin_bit_cast(uint32_t, lo) >> 16);
}

__device__ __forceinline__ void gload_lds16(const void* g, void* l) {
  __builtin_amdgcn_global_load_lds(
      (const __attribute__((address_space(1))) uint32_t*)(uintptr_t)g,
      (__attribute__((address_space(3))) uint32_t*)(uintptr_t)l, 16, 0, 0);
}

// ---------------- fused prep: 4 weight transposes + x convert, ONE launch ----------------
__global__ __launch_bounds__(256) void prep_kernel(const float* __restrict__ x,
                                                   const float* __restrict__ Wq,
                                                   const float* __restrict__ Wk,
                                                   const float* __restrict__ Wv,
                                                   const float* __restrict__ Wo,
                                                   uint16_t* __restrict__ xb,
                                                   uint16_t* __restrict__ Wt3,
                                                   uint16_t* __restrict__ Wot) {
  const int bid = blockIdx.x;
  if (bid < 4096) {
    __shared__ uint16_t tile[32][33];
    const int which = bid >> 10;
    const int tl = bid & 1023;
    const int bx = (tl & 31) * 32;  // n
    const int by = (tl >> 5) * 32;  // k
    const int tx = threadIdx.x & 31;
    const int ty = threadIdx.x >> 5;  // 0..7
    const float* W = (which == 0) ? Wq : (which == 1) ? Wk : (which == 2) ? Wv : Wo;
    uint16_t* Wt = (which < 3) ? (Wt3 + (size_t)which * (1u << 20)) : Wot;
#pragma unroll
    for (int j = 0; j < 4; j++)
      tile[ty + j * 8][tx] = f2bf(W[(size_t)(by + ty + j * 8) * 1024 + bx + tx]);
    __syncthreads();
#pragma unroll
    for (int j = 0; j < 4; j++)
      Wt[(size_t)(bx + ty + j * 8) * 1024 + by + tx] = tile[tx][ty + j * 8];
  } else {
    const int i = (bid - 4096) * 256 + threadIdx.x;  // i < 2M (= NB*NS*ND/4)
    const float4 f = *(const float4*)(x + (size_t)i * 4);
    union { uint16_t u[4]; uint64_t q; } o;
    o.u[0] = f2bf(f.x); o.u[1] = f2bf(f.y); o.u[2] = f2bf(f.z); o.u[3] = f2bf(f.w);
    *(uint64_t*)(xb + (size_t)i * 4) = o.q;
  }
}

// ---------------- GEMM: C[M][c] = A[M][K=1024] * Wt[c][K=1024]^T ----------------
// 256x256 tile, BK=32, 8 waves (512 thr, 2M x 4N), TRIPLE-buffered LDS (96 KB),
// counted-vmcnt pipeline (T3+T4): per K-tile
//   s_waitcnt vmcnt(4); s_barrier   <- raw barrier, tile t+1's 4 loads STAY in flight
//   STAGE(buf[(t+2)%3], t+2)        <- overwrites buffer whose readers the barrier retired
//   12x swizzled ds_read_b128 + 32 MFMA from buf[t%3]
// Loads get ~2 iterations of latency cover (vs <1 in the old drain-to-0 2-phase).
// 64B rows use rotation swizzle chunk' = (chunk+row)&3; staging sources inverse-rotated
// (rule 21). Epilogue: MODE 0 scatters Q/K [BH][S][64] + blocked V [BH][32][64][64];
// MODE 1 writes fp32 C. XCD-chunked supertile decode (NBX = N/256 column tiles).
template <int MODE, int NBX>
__global__ __launch_bounds__(512) void gemm_bt(const uint16_t* __restrict__ A,
                                               const uint16_t* __restrict__ Bt,
                                               uint16_t* __restrict__ O0,
                                               uint16_t* __restrict__ O1,
                                               uint16_t* __restrict__ O2,
                                               float* __restrict__ OF) {
  __shared__ uint16_t lds[3][2][256 * 32];  // 96 KB
  const int tid = threadIdx.x;
  const int lane = tid & 63;
  const int wave = tid >> 6;       // 0..7
  const int wr = wave >> 2;        // 0..1  (row half: 128 rows)
  const int wn = wave & 3;         // 0..3  (col quarter: 64 cols)
  const int l15 = lane & 15, lg = lane >> 4;

  // XCD-chunked supertile decode (8y x 4x supertiles of 256-tiles)
  const int nwg = 32 * NBX;
  const int wg = ((int)blockIdx.x & 7) * (nwg >> 3) + ((int)blockIdx.x >> 3);
  const int st = wg >> 5, in32 = wg & 31;
  const int sy = in32 >> 2, sx = in32 & 3;
  const int stx = st % (NBX / 4), sty = st / (NBX / 4);
  const int row0 = (sty * 8 + sy) * 256;
  const int col0 = (stx * 4 + sx) * 256;

  f32x4 acc[8][4];
#pragma unroll
  for (int i = 0; i < 8; i++)
#pragma unroll
    for (int j = 0; j < 4; j++) acc[i][j] = f32x4{0.f, 0.f, 0.f, 0.f};

  const char* Ag = (const char*)A + (size_t)row0 * 2048;   // 2048 B per K-row
  const char* Bg = (const char*)Bt + (size_t)col0 * 2048;
  char* ldsbase = (char*)&lds[0][0][0];

  // staging: per tile 4 gload_lds16/thread (A j=0..1, B j=0..1); inst j covers rows
  // j*128 + tid>>2; dest chunk = tid&3; inverse-rotation source chunk = ((tid&3)-row)&3
  const int srr = tid >> 2;                     // 0..127
  const int csrc = ((tid & 3) - (srr & 3)) & 3;

#define STAGE_TILE(bs, t)                                                              \
  {                                                                                    \
    char* la = ldsbase + (bs) * 32768 + wave * 1024;                                   \
    char* lb = la + 16384;                                                             \
    _Pragma("unroll") for (int j = 0; j < 2; ++j) {                                    \
      const size_t off = (size_t)(j * 128 + srr) * 2048 + (size_t)(t) * 64 + csrc * 16;\
      gload_lds16(Ag + off, la + j * 8192);                                            \
      gload_lds16(Bg + off, lb + j * 8192);                                            \
    }                                                                                  \
  }

#define COMPUTE_TILE(bc)                                                               \
  {                                                                                    \
    const char* cA = ldsbase + (bc) * 32768;                                           \
    const char* cB = cA + 16384;                                                       \
    bf16x8 af[8], bfr[4];                                                              \
    _Pragma("unroll") for (int ni = 0; ni < 4; ni++) {                                 \
      const int row = wn * 64 + ni * 16 + l15;                                         \
      bfr[ni] = *(const bf16x8*)(cB + row * 64 + ((lg + row) & 3) * 16);               \
    }                                                                                  \
    _Pragma("unroll") for (int mi = 0; mi < 8; mi++) {                                 \
      const int row = wr * 128 + mi * 16 + l15;                                        \
      af[mi] = *(const bf16x8*)(cA + row * 64 + ((lg + row) & 3) * 16);                \
    }                                                                                  \
    _Pragma("unroll") for (int mi = 0; mi < 8; mi++)                                   \
      _Pragma("unroll") for (int ni = 0; ni < 4; ni++)                                 \
        acc[mi][ni] = MFMA16(af[mi], bfr[ni], acc[mi][ni]);                            \
  }

  // prologue: tiles 0,1 in flight (8 insts)
  STAGE_TILE(0, 0);
  STAGE_TILE(1, 1);

  int bc = 0;  // compute buffer = t%3
#pragma unroll 1
  for (int t = 0; t < 31; ++t) {
    // tile t's 4 loads are the oldest; leave tile t+1's 4 in flight
    asm volatile("s_waitcnt vmcnt(4)\n\ts_barrier" ::: "memory");
    if (t < 30) {
      int bs = bc + 2; if (bs >= 3) bs -= 3;
      STAGE_TILE(bs, t + 2);  // overwrites buffer computed at t-1 (barrier retired it)
    }
    COMPUTE_TILE(bc);
    if (++bc == 3) bc = 0;
  }
  asm volatile("s_waitcnt vmcnt(0)\n\ts_barrier" ::: "memory");
  COMPUTE_TILE(bc);

  // Epilogue. C/D layout: col = lane&15, row = (lane>>4)*4 + i  [m89-verified]
#pragma unroll
  for (int mi = 0; mi < 8; mi++) {
#pragma unroll
    for (int ni = 0; ni < 4; ni++) {
      const int c = col0 + wn * 64 + ni * 16 + l15;
      const int rbase = row0 + wr * 128 + mi * 16 + lg * 4;
#pragma unroll
      for (int i = 0; i < 4; i++) {
        const int r = rbase + i;
        const float v = acc[mi][ni][i];
        if (MODE == 0) {
          const int which = c >> 10, cc = c & 1023;
          const int h = cc >> 6, dh = cc & 63;
          const int b = r >> 11, s = r & 2047;
          const size_t hb = (size_t)(b * NH + h);
          if (which == 0)
            O0[(hb * NS + s) * 64 + dh] = f2bf(v * 0.18033688011112042f);  // (1/8)*log2(e)
          else if (which == 1)
            O1[(hb * NS + s) * 64 + dh] = f2bf(v);
          else  // blocked V: [BH][t=s>>6][dh][s&63]
            O2[(((hb * 32 + (s >> 6)) * 64 + dh) * 64) + (s & 63)] = f2bf(v);
        } else {
          OF[(size_t)r * 1024 + c] = v;
        }
      }
    }
  }
#undef STAGE_TILE
#undef COMPUTE_TILE
}

// ---- stage one (K,V) tile pair (8KB each, contiguous) into wave-private LDS ----
// Inverse-rotation source swizzle (rule 21): LDS dest linear (wave-uniform base +
// lane*16); per-lane global src byte zs = row*128 + ((chunk - row&7)&7)*16 so that a
// reader using chunk' = (chunk + row&7)&7 sees the logical row-major tile.
__device__ __forceinline__ void stage_kv(const char* __restrict__ Kg,
                                         const char* __restrict__ Vg,
                                         char* kl, char* vl, int lane) {
#pragma unroll
  for (int j = 0; j < 8; ++j) {
    const int y = j * 1024 + lane * 16;
    const int r = y >> 7;
    const int zs = (r << 7) | ((((y >> 4) - r) & 7) << 4);
    gload_lds16(Kg + zs, kl + j * 1024);
    gload_lds16(Vg + zs, vl + j * 1024);
  }
}

// ---- one 32-row attention unit (round-19 structure + T5 setprio on PV cluster) ----
__device__ __forceinline__ void attn_unit(const uint16_t* __restrict__ Qh,
                                          const char* __restrict__ Kg,
                                          const char* __restrict__ Vg,
                                          uint16_t* __restrict__ Aout,
                                          int b, int h, int gp, int l15, int lg, int lane,
                                          char* kl, char* vl,
                                          uint16_t (*pX)[64][16]) {
  const int qbA = gp * 32;
  const int qbB = qbA + 16;
  const int tmax = gp >> 1;          // same last tile for both chains
  const int nfdA = (2 * gp) & 3;     // 0 or 2
  const int nfdB = nfdA + 1;

  // stage tile 0 (overlaps Q-fragment loads below)
  stage_kv(Kg, Vg, kl, vl, lane);

  const bf16x8 qfA0 = *(const bf16x8*)&Qh[(size_t)(qbA + l15) * 64 + lg * 8];
  const bf16x8 qfA1 = *(const bf16x8*)&Qh[(size_t)(qbA + l15) * 64 + 32 + lg * 8];
  const bf16x8 qfB0 = *(const bf16x8*)&Qh[(size_t)(qbB + l15) * 64 + lg * 8];
  const bf16x8 qfB1 = *(const bf16x8*)&Qh[(size_t)(qbB + l15) * 64 + 32 + lg * 8];

  const short one_bf = (short)0x3F80;  // bf16 1.0
  const bf16x8 ones = {one_bf, one_bf, one_bf, one_bf, one_bf, one_bf, one_bf, one_bf};

  const int rsw = l15 & 7;  // row&7 for both K rows (nf*16+l15) and V rows (df*16+l15)

  // P write col (u16): chunk' = (lg + (k>>2))&3 with (k>>2)&3 == l15>>2 (k=nf*16+l15)
  const int wcol = ((lg + (l15 >> 2)) & 3) * 4;
  // P tr-read per-lane swizzled addresses (round-16, verified)
  const int rr = l15 >> 2, cc0 = l15 & 3;
  const int rot = (2 * lg) & 3;
  const uint32_t pb = (uint32_t)(uintptr_t)&pX[0][0][0];
  const uint32_t addr0 = pb + (uint32_t)(lg * 256 + rr * 32 + (((cc0 + rot) & 3) * 8));
  const uint32_t addr1 = pb + (uint32_t)(lg * 256 + 128 + rr * 32 + (((cc0 + rot + 1) & 3) * 8));

  f32x4 oA[4], oB[4];
  f32x4 rsA = f32x4{0.f, 0.f, 0.f, 0.f};
  f32x4 rsB = f32x4{0.f, 0.f, 0.f, 0.f};
#pragma unroll
  for (int i = 0; i < 4; i++) {
    oA[i] = f32x4{0.f, 0.f, 0.f, 0.f};
    oB[i] = f32x4{0.f, 0.f, 0.f, 0.f};
  }

  for (int t = 0; t <= tmax; ++t) {
    // wait for this tile's staging to land (compiler can't see gload_lds->ds_read dep)
    asm volatile("s_waitcnt vmcnt(0)" ::: "memory");
    // read ALL K and V fragments into registers (rotation-swizzled ds_read_b128)
    bf16x8 kf[4][2], vf[4][2];
#pragma unroll
    for (int nf = 0; nf < 4; ++nf)
#pragma unroll
      for (int kk = 0; kk < 2; ++kk) {
        const int off = (nf * 16 + l15) * 128 + (((kk * 4 + lg) + rsw) & 7) * 16;
        kf[nf][kk] = *(const bf16x8*)(kl + off);
        vf[nf][kk] = *(const bf16x8*)(vl + off);
      }
    // drain reads before the texture unit may overwrite the buffers (correctness)
    asm volatile("s_waitcnt lgkmcnt(0)" ::: "memory");
    // prefetch next tile (frags are in regs; overwrites the buffers)
    if (t < tmax) stage_kv(Kg + (size_t)(t + 1) * 8192, Vg + (size_t)(t + 1) * 8192, kl, vl, lane);

    const int nfmA = (t == tmax) ? nfdA : 3;
    const int nfmB = (t == tmax) ? nfdB : 3;
#pragma unroll
    for (int nf = 0; nf < 4; ++nf) {
      if (nf <= nfmB) {
        f32x4 a = f32x4{0.f, 0.f, 0.f, 0.f};
        a = MFMA16(qfB0, kf[nf][0], a);
        a = MFMA16(qfB1, kf[nf][1], a);
        if (t == tmax && nf == nfdB) {  // chain-B diagonal fragment: mask col > row
#pragma unroll
          for (int i = 0; i < 4; i++)
            if (l15 > lg * 4 + i) a[i] = -1e30f;
        }
        {
          const float e0 = exp2f(a[0]), e1 = exp2f(a[1]);
          const float e2 = exp2f(a[2]), e3 = exp2f(a[3]);
          *(uint64_t*)&pX[1][nf * 16 + l15][wcol] =
              ((uint64_t)pk2(e2, e3) << 32) | pk2(e0, e1);
        }
        if (nf <= nfmA) {
          f32x4 c = f32x4{0.f, 0.f, 0.f, 0.f};
          c = MFMA16(qfA0, kf[nf][0], c);
          c = MFMA16(qfA1, kf[nf][1], c);
          if (t == tmax && nf == nfdA) {
#pragma unroll
            for (int i = 0; i < 4; i++)
              if (l15 > lg * 4 + i) c[i] = -1e30f;
          }
          const float e0 = exp2f(c[0]), e1 = exp2f(c[1]);
          const float e2 = exp2f(c[2]), e3 = exp2f(c[3]);
          *(uint64_t*)&pX[0][nf * 16 + l15][wcol] =
              ((uint64_t)pk2(e2, e3) << 32) | pk2(e0, e1);
        } else {
          *(uint64_t*)&pX[0][nf * 16 + l15][wcol] = 0ull;
        }
      } else {
        *(uint64_t*)&pX[0][nf * 16 + l15][wcol] = 0ull;
        *(uint64_t*)&pX[1][nf * 16 + l15][wcol] = 0ull;
      }
    }
    // transpose-read P fragments (waitcnt inside; MFMA data-depends on outputs)
    u32x2 a0, a1, a2, a3, b0, b1, b2, b3;
    asm volatile(
        "ds_read_b64_tr_b16 %0, %8\n\t"
        "ds_read_b64_tr_b16 %1, %9\n\t"
        "ds_read_b64_tr_b16 %2, %8 offset:1024\n\t"
        "ds_read_b64_tr_b16 %3, %9 offset:1024\n\t"
        "ds_read_b64_tr_b16 %4, %8 offset:2048\n\t"
        "ds_read_b64_tr_b16 %5, %9 offset:2048\n\t"
        "ds_read_b64_tr_b16 %6, %8 offset:3072\n\t"
        "ds_read_b64_tr_b16 %7, %9 offset:3072\n\t"
        "s_waitcnt lgkmcnt(0)"
        : "=&v"(a0), "=&v"(a1), "=&v"(a2), "=&v"(a3),
          "=&v"(b0), "=&v"(b1), "=&v"(b2), "=&v"(b3)
        : "v"(addr0), "v"(addr1)
        : "memory");
    union { u32x2 u2[2]; bf16x8 v8; } uA0, uA1, uB0, uB1;
    uA0.u2[0] = a0; uA0.u2[1] = a1;  // k = lg*8 + 0..7
    uA1.u2[0] = a2; uA1.u2[1] = a3;  // k = 32 + lg*8 + 0..7
    uB0.u2[0] = b0; uB0.u2[1] = b1;
    uB1.u2[0] = b2; uB1.u2[1] = b3;
    const bf16x8 paA0 = uA0.v8, paA1 = uA1.v8;
    const bf16x8 paB0 = uB0.v8, paB1 = uB1.v8;
    // pure-MFMA PV cluster: favor this wave while others issue memory (T5)
    __builtin_amdgcn_s_setprio(1);
    rsA = MFMA16(paA0, ones, rsA);
    rsA = MFMA16(paA1, ones, rsA);
    rsB = MFMA16(paB0, ones, rsB);
    rsB = MFMA16(paB1, ones, rsB);
#pragma unroll
    for (int df = 0; df < 4; ++df) {
      oA[df] = MFMA16(paA0, vf[df][0], oA[df]);
      oA[df] = MFMA16(paA1, vf[df][1], oA[df]);
      oB[df] = MFMA16(paB0, vf[df][0], oB[df]);
      oB[df] = MFMA16(paB1, vf[df][1], oB[df]);
    }
    __builtin_amdgcn_s_setprio(0);
  }

#pragma unroll
  for (int df = 0; df < 4; ++df) {
#pragma unroll
    for (int i = 0; i < 4; i++) {
      const int qA = qbA + lg * 4 + i;
      const int qB = qbB + lg * 4 + i;
      Aout[((size_t)(b * NS + qA)) * 1024 + h * 64 + df * 16 + l15] = f2bf(oA[df][i] / rsA[i]);
      Aout[((size_t)(b * NS + qB)) * 1024 + h * 64 + df * 16 + l15] = f2bf(oB[df][i] / rsB[i]);
    }
  }
}

// ---------------- causal flash attention (wave = two sequential balanced units) ----------------
__global__ __launch_bounds__(256) void attn_fwd(const uint16_t* __restrict__ Q,
                                                const uint16_t* __restrict__ K,
                                                const uint16_t* __restrict__ Vt,
                                                uint16_t* __restrict__ Aout) {
  const int bid = blockIdx.x;
  const int xcd = bid & 7;
  const int sp = (bid >> 3) & 3;
  const int gblk = bid >> 5;  // 0..15

  const int w = threadIdx.x >> 6;
  const int lane = threadIdx.x & 63;
  const int l15 = lane & 15, lg = lane >> 4;
  const int g = gblk * 4 + w;  // 0..63

  __shared__ __align__(16) uint16_t plds[4][2][64][16];  // P buffers (16 KB)
  __shared__ __align__(16) char kstage[4][8192];         // K tiles  (32 KB)
  __shared__ __align__(16) char vstage[4][8192];         // V tiles  (32 KB)

  for (int seg = 0; seg < 2; ++seg) {
    const int slot = sp * 2 + seg;
    const int bh = (slot << 3) | xcd;
    const int gp = seg ? (63 - g) : g;
    const uint16_t* Qh = Q + (size_t)bh * (NS * 64);
    const char* Kg = (const char*)(K + (size_t)bh * (NS * 64));        // tiles at t*8192 B
    const char* Vg = (const char*)(Vt + (size_t)bh * (32 * 64 * 64));  // blocked tiles
    attn_unit(Qh, Kg, Vg, Aout, bh >> 4, bh & 15, gp, l15, lg, lane,
              kstage[w], vstage[w], plds[w]);
  }
}

extern "C" void kernel_launch(void* const* d_in, const int* in_sizes, int n_in,
                              void* d_out, int out_size, void* d_ws, size_t ws_size,
                              hipStream_t stream) {
  const float* x = (const float*)d_in[0];
  const float* Wq = (const float*)d_in[1];
  const float* Wk = (const float*)d_in[2];
  const float* Wv = (const float*)d_in[3];
  const float* Wo = (const float*)d_in[4];
  float* out = (float*)d_out;

  char* ws = (char*)d_ws;
  uint16_t* xb = (uint16_t*)(ws);                        // 16 MB  (reused as attn buffer)
  uint16_t* Wt3 = (uint16_t*)(ws + (16u << 20));         // 6 MB   [3][1024][1024] (n-major)
  uint16_t* Wot = (uint16_t*)(ws + (22u << 20));         // 2 MB
  uint16_t* Qb = (uint16_t*)(ws + (24u << 20));          // 16 MB  [BH][S][64]
  uint16_t* Kb = (uint16_t*)(ws + (40u << 20));          // 16 MB  [BH][S][64]
  uint16_t* Vt = (uint16_t*)(ws + (56u << 20));          // 16 MB  blocked [BH][32][64][64]
  uint16_t* attn = xb;                                   // total 72 MB

  prep_kernel<<<12288, 256, 0, stream>>>(x, Wq, Wk, Wv, Wo, xb, Wt3, Wot);

  gemm_bt<0, 12><<<384, 512, 0, stream>>>(xb, Wt3, Qb, Kb, Vt, nullptr);
  attn_fwd<<<512, 256, 0, stream>>>(Qb, Kb, Vt, attn);
  gemm_bt<1, 4><<<128, 512, 0, stream>>>(attn, Wot, nullptr, nullptr, nullptr, out);
}

// Round 25
// 185.033 us; speedup vs baseline: 1.1464x; 1.1464x over previous
//
#include <hip/hip_runtime.h>
#include <stdint.h>

// Shapes (fixed): B=4, S=2048, D=1024, H=16, DH=64
#define NB 4
#define NS 2048
#define ND 1024
#define NH 16
#define NDH 64

typedef __attribute__((ext_vector_type(8))) short bf16x8;
typedef __attribute__((ext_vector_type(4))) float f32x4;
typedef __attribute__((ext_vector_type(2))) unsigned int u32x2;

#define MFMA16(a, b, c) __builtin_amdgcn_mfma_f32_16x16x32_bf16((a), (b), (c), 0, 0, 0)

__device__ __forceinline__ uint16_t f2bf(float f) {
  uint32_t u = __builtin_bit_cast(uint32_t, f);
  return (uint16_t)((u + 0x7FFFu + ((u >> 16) & 1u)) >> 16);
}

// truncating bf16x2 pack (P values; downward bias cancels in o/rs ratio).
__device__ __forceinline__ uint32_t pk2(float lo, float hi) {
  return (__builtin_bit_cast(uint32_t, hi) & 0xFFFF0000u) |
         (__builtin_bit_cast(uint32_t, lo) >> 16);
}

__device__ __forceinline__ void gload_lds16(const void* g, void* l) {
  __builtin_amdgcn_global_load_lds(
      (const __attribute__((address_space(1))) uint32_t*)(uintptr_t)g,
      (__attribute__((address_space(3))) uint32_t*)(uintptr_t)l, 16, 0, 0);
}

// ---------------- fused prep: 4 weight transposes + x convert, ONE launch ----------------
__global__ __launch_bounds__(256) void prep_kernel(const float* __restrict__ x,
                                                   const float* __restrict__ Wq,
                                                   const float* __restrict__ Wk,
                                                   const float* __restrict__ Wv,
                                                   const float* __restrict__ Wo,
                                                   uint16_t* __restrict__ xb,
                                                   uint16_t* __restrict__ Wt3,
                                                   uint16_t* __restrict__ Wot) {
  const int bid = blockIdx.x;
  if (bid < 4096) {
    __shared__ uint16_t tile[32][33];
    const int which = bid >> 10;
    const int tl = bid & 1023;
    const int bx = (tl & 31) * 32;  // n
    const int by = (tl >> 5) * 32;  // k
    const int tx = threadIdx.x & 31;
    const int ty = threadIdx.x >> 5;  // 0..7
    const float* W = (which == 0) ? Wq : (which == 1) ? Wk : (which == 2) ? Wv : Wo;
    uint16_t* Wt = (which < 3) ? (Wt3 + (size_t)which * (1u << 20)) : Wot;
#pragma unroll
    for (int j = 0; j < 4; j++)
      tile[ty + j * 8][tx] = f2bf(W[(size_t)(by + ty + j * 8) * 1024 + bx + tx]);
    __syncthreads();
#pragma unroll
    for (int j = 0; j < 4; j++)
      Wt[(size_t)(bx + ty + j * 8) * 1024 + by + tx] = tile[tx][ty + j * 8];
  } else {
    const int i = (bid - 4096) * 256 + threadIdx.x;  // i < 2M (= NB*NS*ND/4)
    const float4 f = *(const float4*)(x + (size_t)i * 4);
    union { uint16_t u[4]; uint64_t q; } o;
    o.u[0] = f2bf(f.x); o.u[1] = f2bf(f.y); o.u[2] = f2bf(f.z); o.u[3] = f2bf(f.w);
    *(uint64_t*)(xb + (size_t)i * 4) = o.q;
  }
}

// ---------------- GEMM: C[M][c] = A[M][K=1024] * Wt[c][K=1024]^T ----------------
// 128x128 tile, BK=32, 4 waves, TRIPLE-buffered LDS (48 KB -> 3 blocks/CU), counted
// vmcnt pipeline: per K-tile
//   s_waitcnt vmcnt(4); s_barrier   <- tile t+1's 4 loads/thread STAY in flight
//   STAGE(buf[(t+2)%3], t+2)        <- overwrites buffer whose readers the barrier retired
//   8x swizzled ds_read_b128 + 16 MFMA from buf[t%3]
// Loads get ~2 iterations of latency cover; 3 co-resident blocks hide barrier skew
// (round-24 lesson: 96KB/1-block/CU exposed every stall). 64B rows use rotation
// swizzle chunk' = (chunk+row)&3, staging source inverse-rotated (rule 21).
// MODE 0: QKV projection: Q/K scatter [BH][S][64], blocked V [BH][32][64][64].
// MODE 1: out projection, fp32 C. XCD-chunked supertile decode (T1 + L2 blocking).
template <int MODE, int NBX>
__global__ __launch_bounds__(256) void gemm_bt(const uint16_t* __restrict__ A,
                                               const uint16_t* __restrict__ Bt,
                                               uint16_t* __restrict__ O0,
                                               uint16_t* __restrict__ O1,
                                               uint16_t* __restrict__ O2,
                                               float* __restrict__ OF) {
  __shared__ uint16_t lds[3][2][128 * 32];  // [buf][A/B][128 rows x 32 cols] = 48 KB
  const int tid = threadIdx.x;
  const int lane = tid & 63;
  const int wave = tid >> 6;
  const int wr = wave >> 1, wc = wave & 1;
  const int l15 = lane & 15, lg = lane >> 4;

  // XCD-chunked supertile decode
  const int nwg = NBX * 64;
  const int wg = ((int)blockIdx.x & 7) * (nwg >> 3) + ((int)blockIdx.x >> 3);
  const int st = wg >> 5, in32 = wg & 31;
  const int sy = in32 >> 2, sx = in32 & 3;
  const int stx = st % (NBX / 4), sty = st / (NBX / 4);
  const int row0 = (sty * 8 + sy) * 128;
  const int col0 = (stx * 4 + sx) * 128;

  f32x4 acc[4][4];
#pragma unroll
  for (int i = 0; i < 4; i++)
#pragma unroll
    for (int j = 0; j < 4; j++) acc[i][j] = f32x4{0.f, 0.f, 0.f, 0.f};

  const char* Ag = (const char*)A + (size_t)row0 * 2048;  // 2048 B per K-row
  const char* Bg = (const char*)Bt + (size_t)col0 * 2048;
  char* ldsbase = (char*)&lds[0][0][0];

  // staging: 2 A + 2 B gload_lds16/thread per tile; inst j covers rows j*64 + tid>>2.
  // dest byte y = j*4096 + tid*16 -> row = j*64+srr, chunk = tid&3.
  // inverse-rotation source chunk: csrc = ((tid&3) - (srr&3)) & 3  (j*64 == 0 mod 4)
  const int srr = tid >> 2;                     // 0..63
  const int csrc = ((tid & 3) - (srr & 3)) & 3;

#define STAGE_TILE(bs, t)                                                              \
  {                                                                                    \
    char* la = ldsbase + (bs) * 16384 + wave * 1024;                                   \
    char* lb = la + 8192;                                                              \
    _Pragma("unroll") for (int j = 0; j < 2; ++j) {                                    \
      const size_t off = (size_t)(j * 64 + srr) * 2048 + (size_t)(t) * 64 + csrc * 16; \
      gload_lds16(Ag + off, la + j * 4096);                                            \
      gload_lds16(Bg + off, lb + j * 4096);                                            \
    }                                                                                  \
  }

#define COMPUTE_TILE(bc)                                                               \
  {                                                                                    \
    const char* cA = ldsbase + (bc) * 16384;                                           \
    const char* cB = cA + 8192;                                                        \
    bf16x8 af[4], bfr[4];                                                              \
    _Pragma("unroll") for (int ni = 0; ni < 4; ni++) {                                 \
      const int row = wc * 64 + ni * 16 + l15;                                         \
      bfr[ni] = *(const bf16x8*)(cB + row * 64 + ((lg + row) & 3) * 16);               \
    }                                                                                  \
    _Pragma("unroll") for (int mi = 0; mi < 4; mi++) {                                 \
      const int row = wr * 64 + mi * 16 + l15;                                         \
      af[mi] = *(const bf16x8*)(cA + row * 64 + ((lg + row) & 3) * 16);                \
    }                                                                                  \
    _Pragma("unroll") for (int mi = 0; mi < 4; mi++)                                   \
      _Pragma("unroll") for (int ni = 0; ni < 4; ni++)                                 \
        acc[mi][ni] = MFMA16(af[mi], bfr[ni], acc[mi][ni]);                            \
  }

  // prologue: tiles 0,1 in flight (8 loads/thread)
  STAGE_TILE(0, 0);
  STAGE_TILE(1, 1);

  int bc = 0;  // compute buffer = t%3
#pragma unroll 1
  for (int t = 0; t < 31; ++t) {
    // wait for tile t's 4 loads (oldest); tile t+1's 4 stay in flight across barrier
    asm volatile("s_waitcnt vmcnt(4)\n\ts_barrier" ::: "memory");
    if (t < 30) {
      int bs = bc + 2; if (bs >= 3) bs -= 3;
      STAGE_TILE(bs, t + 2);  // overwrites buffer computed at t-1 (barrier retired it)
    }
    COMPUTE_TILE(bc);
    if (++bc == 3) bc = 0;
  }
  asm volatile("s_waitcnt vmcnt(0)\n\ts_barrier" ::: "memory");
  COMPUTE_TILE(bc);

  // Epilogue. C/D layout: col = lane&15, row = (lane>>4)*4 + i  [m89-verified]
#pragma unroll
  for (int mi = 0; mi < 4; mi++) {
#pragma unroll
    for (int ni = 0; ni < 4; ni++) {
      const int c = col0 + wc * 64 + ni * 16 + l15;
      const int rbase = row0 + wr * 64 + mi * 16 + lg * 4;
#pragma unroll
      for (int i = 0; i < 4; i++) {
        const int r = rbase + i;
        const float v = acc[mi][ni][i];
        if (MODE == 0) {
          const int which = c >> 10, cc = c & 1023;
          const int h = cc >> 6, dh = cc & 63;
          const int b = r >> 11, s = r & 2047;
          const size_t hb = (size_t)(b * NH + h);
          if (which == 0)
            O0[(hb * NS + s) * 64 + dh] = f2bf(v * 0.18033688011112042f);  // (1/8)*log2(e)
          else if (which == 1)
            O1[(hb * NS + s) * 64 + dh] = f2bf(v);
          else  // blocked V: [BH][t=s>>6][dh][s&63]
            O2[(((hb * 32 + (s >> 6)) * 64 + dh) * 64) + (s & 63)] = f2bf(v);
        } else {
          OF[(size_t)r * 1024 + c] = v;
        }
      }
    }
  }
#undef STAGE_TILE
#undef COMPUTE_TILE
}

// ---- stage one (K,V) tile pair (8KB each, contiguous) into wave-private LDS ----
// Inverse-rotation source swizzle (rule 21): LDS dest linear (wave-uniform base +
// lane*16); per-lane global src byte zs = row*128 + ((chunk - row&7)&7)*16 so that a
// reader using chunk' = (chunk + row&7)&7 sees the logical row-major tile.
__device__ __forceinline__ void stage_kv(const char* __restrict__ Kg,
                                         const char* __restrict__ Vg,
                                         char* kl, char* vl, int lane) {
#pragma unroll
  for (int j = 0; j < 8; ++j) {
    const int y = j * 1024 + lane * 16;
    const int r = y >> 7;
    const int zs = (r << 7) | ((((y >> 4) - r) & 7) << 4);
    gload_lds16(Kg + zs, kl + j * 1024);
    gload_lds16(Vg + zs, vl + j * 1024);
  }
}

// ---- one 32-row attention unit (round-19 structure + T5 setprio on PV cluster) ----
__device__ __forceinline__ void attn_unit(const uint16_t* __restrict__ Qh,
                                          const char* __restrict__ Kg,
                                          const char* __restrict__ Vg,
                                          uint16_t* __restrict__ Aout,
                                          int b, int h, int gp, int l15, int lg, int lane,
                                          char* kl, char* vl,
                                          uint16_t (*pX)[64][16]) {
  const int qbA = gp * 32;
  const int qbB = qbA + 16;
  const int tmax = gp >> 1;          // same last tile for both chains
  const int nfdA = (2 * gp) & 3;     // 0 or 2
  const int nfdB = nfdA + 1;

  // stage tile 0 (overlaps Q-fragment loads below)
  stage_kv(Kg, Vg, kl, vl, lane);

  const bf16x8 qfA0 = *(const bf16x8*)&Qh[(size_t)(qbA + l15) * 64 + lg * 8];
  const bf16x8 qfA1 = *(const bf16x8*)&Qh[(size_t)(qbA + l15) * 64 + 32 + lg * 8];
  const bf16x8 qfB0 = *(const bf16x8*)&Qh[(size_t)(qbB + l15) * 64 + lg * 8];
  const bf16x8 qfB1 = *(const bf16x8*)&Qh[(size_t)(qbB + l15) * 64 + 32 + lg * 8];

  const short one_bf = (short)0x3F80;  // bf16 1.0
  const bf16x8 ones = {one_bf, one_bf, one_bf, one_bf, one_bf, one_bf, one_bf, one_bf};

  const int rsw = l15 & 7;  // row&7 for both K rows (nf*16+l15) and V rows (df*16+l15)

  // P write col (u16): chunk' = (lg + (k>>2))&3 with (k>>2)&3 == l15>>2 (k=nf*16+l15)
  const int wcol = ((lg + (l15 >> 2)) & 3) * 4;
  // P tr-read per-lane swizzled addresses (round-16, verified)
  const int rr = l15 >> 2, cc0 = l15 & 3;
  const int rot = (2 * lg) & 3;
  const uint32_t pb = (uint32_t)(uintptr_t)&pX[0][0][0];
  const uint32_t addr0 = pb + (uint32_t)(lg * 256 + rr * 32 + (((cc0 + rot) & 3) * 8));
  const uint32_t addr1 = pb + (uint32_t)(lg * 256 + 128 + rr * 32 + (((cc0 + rot + 1) & 3) * 8));

  f32x4 oA[4], oB[4];
  f32x4 rsA = f32x4{0.f, 0.f, 0.f, 0.f};
  f32x4 rsB = f32x4{0.f, 0.f, 0.f, 0.f};
#pragma unroll
  for (int i = 0; i < 4; i++) {
    oA[i] = f32x4{0.f, 0.f, 0.f, 0.f};
    oB[i] = f32x4{0.f, 0.f, 0.f, 0.f};
  }

  for (int t = 0; t <= tmax; ++t) {
    // wait for this tile's staging to land (compiler can't see gload_lds->ds_read dep)
    asm volatile("s_waitcnt vmcnt(0)" ::: "memory");
    // read ALL K and V fragments into registers (rotation-swizzled ds_read_b128)
    bf16x8 kf[4][2], vf[4][2];
#pragma unroll
    for (int nf = 0; nf < 4; ++nf)
#pragma unroll
      for (int kk = 0; kk < 2; ++kk) {
        const int off = (nf * 16 + l15) * 128 + (((kk * 4 + lg) + rsw) & 7) * 16;
        kf[nf][kk] = *(const bf16x8*)(kl + off);
        vf[nf][kk] = *(const bf16x8*)(vl + off);
      }
    // drain reads before the texture unit may overwrite the buffers (correctness)
    asm volatile("s_waitcnt lgkmcnt(0)" ::: "memory");
    // prefetch next tile (frags are in regs; overwrites the buffers)
    if (t < tmax) stage_kv(Kg + (size_t)(t + 1) * 8192, Vg + (size_t)(t + 1) * 8192, kl, vl, lane);

    const int nfmA = (t == tmax) ? nfdA : 3;
    const int nfmB = (t == tmax) ? nfdB : 3;
#pragma unroll
    for (int nf = 0; nf < 4; ++nf) {
      if (nf <= nfmB) {
        f32x4 a = f32x4{0.f, 0.f, 0.f, 0.f};
        a = MFMA16(qfB0, kf[nf][0], a);
        a = MFMA16(qfB1, kf[nf][1], a);
        if (t == tmax && nf == nfdB) {  // chain-B diagonal fragment: mask col > row
#pragma unroll
          for (int i = 0; i < 4; i++)
            if (l15 > lg * 4 + i) a[i] = -1e30f;
        }
        {
          const float e0 = exp2f(a[0]), e1 = exp2f(a[1]);
          const float e2 = exp2f(a[2]), e3 = exp2f(a[3]);
          *(uint64_t*)&pX[1][nf * 16 + l15][wcol] =
              ((uint64_t)pk2(e2, e3) << 32) | pk2(e0, e1);
        }
        if (nf <= nfmA) {
          f32x4 c = f32x4{0.f, 0.f, 0.f, 0.f};
          c = MFMA16(qfA0, kf[nf][0], c);
          c = MFMA16(qfA1, kf[nf][1], c);
          if (t == tmax && nf == nfdA) {
#pragma unroll
            for (int i = 0; i < 4; i++)
              if (l15 > lg * 4 + i) c[i] = -1e30f;
          }
          const float e0 = exp2f(c[0]), e1 = exp2f(c[1]);
          const float e2 = exp2f(c[2]), e3 = exp2f(c[3]);
          *(uint64_t*)&pX[0][nf * 16 + l15][wcol] =
              ((uint64_t)pk2(e2, e3) << 32) | pk2(e0, e1);
        } else {
          *(uint64_t*)&pX[0][nf * 16 + l15][wcol] = 0ull;
        }
      } else {
        *(uint64_t*)&pX[0][nf * 16 + l15][wcol] = 0ull;
        *(uint64_t*)&pX[1][nf * 16 + l15][wcol] = 0ull;
      }
    }
    // transpose-read P fragments (waitcnt inside; MFMA data-depends on outputs)
    u32x2 a0, a1, a2, a3, b0, b1, b2, b3;
    asm volatile(
        "ds_read_b64_tr_b16 %0, %8\n\t"
        "ds_read_b64_tr_b16 %1, %9\n\t"
        "ds_read_b64_tr_b16 %2, %8 offset:1024\n\t"
        "ds_read_b64_tr_b16 %3, %9 offset:1024\n\t"
        "ds_read_b64_tr_b16 %4, %8 offset:2048\n\t"
        "ds_read_b64_tr_b16 %5, %9 offset:2048\n\t"
        "ds_read_b64_tr_b16 %6, %8 offset:3072\n\t"
        "ds_read_b64_tr_b16 %7, %9 offset:3072\n\t"
        "s_waitcnt lgkmcnt(0)"
        : "=&v"(a0), "=&v"(a1), "=&v"(a2), "=&v"(a3),
          "=&v"(b0), "=&v"(b1), "=&v"(b2), "=&v"(b3)
        : "v"(addr0), "v"(addr1)
        : "memory");
    union { u32x2 u2[2]; bf16x8 v8; } uA0, uA1, uB0, uB1;
    uA0.u2[0] = a0; uA0.u2[1] = a1;  // k = lg*8 + 0..7
    uA1.u2[0] = a2; uA1.u2[1] = a3;  // k = 32 + lg*8 + 0..7
    uB0.u2[0] = b0; uB0.u2[1] = b1;
    uB1.u2[0] = b2; uB1.u2[1] = b3;
    const bf16x8 paA0 = uA0.v8, paA1 = uA1.v8;
    const bf16x8 paB0 = uB0.v8, paB1 = uB1.v8;
    // pure-MFMA PV cluster: favor this wave while others issue memory (T5)
    __builtin_amdgcn_s_setprio(1);
    rsA = MFMA16(paA0, ones, rsA);
    rsA = MFMA16(paA1, ones, rsA);
    rsB = MFMA16(paB0, ones, rsB);
    rsB = MFMA16(paB1, ones, rsB);
#pragma unroll
    for (int df = 0; df < 4; ++df) {
      oA[df] = MFMA16(paA0, vf[df][0], oA[df]);
      oA[df] = MFMA16(paA1, vf[df][1], oA[df]);
      oB[df] = MFMA16(paB0, vf[df][0], oB[df]);
      oB[df] = MFMA16(paB1, vf[df][1], oB[df]);
    }
    __builtin_amdgcn_s_setprio(0);
  }

#pragma unroll
  for (int df = 0; df < 4; ++df) {
#pragma unroll
    for (int i = 0; i < 4; i++) {
      const int qA = qbA + lg * 4 + i;
      const int qB = qbB + lg * 4 + i;
      Aout[((size_t)(b * NS + qA)) * 1024 + h * 64 + df * 16 + l15] = f2bf(oA[df][i] / rsA[i]);
      Aout[((size_t)(b * NS + qB)) * 1024 + h * 64 + df * 16 + l15] = f2bf(oB[df][i] / rsB[i]);
    }
  }
}

// ---------------- causal flash attention (wave = two sequential balanced units) ----------------
__global__ __launch_bounds__(256) void attn_fwd(const uint16_t* __restrict__ Q,
                                                const uint16_t* __restrict__ K,
                                                const uint16_t* __restrict__ Vt,
                                                uint16_t* __restrict__ Aout) {
  const int bid = blockIdx.x;
  const int xcd = bid & 7;
  const int sp = (bid >> 3) & 3;
  const int gblk = bid >> 5;  // 0..15

  const int w = threadIdx.x >> 6;
  const int lane = threadIdx.x & 63;
  const int l15 = lane & 15, lg = lane >> 4;
  const int g = gblk * 4 + w;  // 0..63

  __shared__ __align__(16) uint16_t plds[4][2][64][16];  // P buffers (16 KB)
  __shared__ __align__(16) char kstage[4][8192];         // K tiles  (32 KB)
  __shared__ __align__(16) char vstage[4][8192];         // V tiles  (32 KB)

  for (int seg = 0; seg < 2; ++seg) {
    const int slot = sp * 2 + seg;
    const int bh = (slot << 3) | xcd;
    const int gp = seg ? (63 - g) : g;
    const uint16_t* Qh = Q + (size_t)bh * (NS * 64);
    const char* Kg = (const char*)(K + (size_t)bh * (NS * 64));        // tiles at t*8192 B
    const char* Vg = (const char*)(Vt + (size_t)bh * (32 * 64 * 64));  // blocked tiles
    attn_unit(Qh, Kg, Vg, Aout, bh >> 4, bh & 15, gp, l15, lg, lane,
              kstage[w], vstage[w], plds[w]);
  }
}

extern "C" void kernel_launch(void* const* d_in, const int* in_sizes, int n_in,
                              void* d_out, int out_size, void* d_ws, size_t ws_size,
                              hipStream_t stream) {
  const float* x = (const float*)d_in[0];
  const float* Wq = (const float*)d_in[1];
  const float* Wk = (const float*)d_in[2];
  const float* Wv = (const float*)d_in[3];
  const float* Wo = (const float*)d_in[4];
  float* out = (float*)d_out;

  char* ws = (char*)d_ws;
  uint16_t* xb = (uint16_t*)(ws);                        // 16 MB  (reused as attn buffer)
  uint16_t* Wt3 = (uint16_t*)(ws + (16u << 20));         // 6 MB   [3][1024][1024] (n-major)
  uint16_t* Wot = (uint16_t*)(ws + (22u << 20));         // 2 MB
  uint16_t* Qb = (uint16_t*)(ws + (24u << 20));          // 16 MB  [BH][S][64]
  uint16_t* Kb = (uint16_t*)(ws + (40u << 20));          // 16 MB  [BH][S][64]
  uint16_t* Vt = (uint16_t*)(ws + (56u << 20));          // 16 MB  blocked [BH][32][64][64]
  uint16_t* attn = xb;                                   // total 72 MB

  prep_kernel<<<12288, 256, 0, stream>>>(x, Wq, Wk, Wv, Wo, xb, Wt3, Wot);

  gemm_bt<0, 24><<<1536, 256, 0, stream>>>(xb, Wt3, Qb, Kb, Vt, nullptr);
  attn_fwd<<<512, 256, 0, stream>>>(Qb, Kb, Vt, attn);
  gemm_bt<1, 8><<<512, 256, 0, stream>>>(attn, Wot, nullptr, nullptr, nullptr, out);
}

// Round 26
// 182.750 us; speedup vs baseline: 1.1607x; 1.0125x over previous
//
#include <hip/hip_runtime.h>
#include <stdint.h>

// Shapes (fixed): B=4, S=2048, D=1024, H=16, DH=64
#define NB 4
#define NS 2048
#define ND 1024
#define NH 16
#define NDH 64

typedef __attribute__((ext_vector_type(8))) short bf16x8;
typedef __attribute__((ext_vector_type(4))) float f32x4;
typedef __attribute__((ext_vector_type(2))) unsigned int u32x2;

#define MFMA16(a, b, c) __builtin_amdgcn_mfma_f32_16x16x32_bf16((a), (b), (c), 0, 0, 0)

__device__ __forceinline__ uint16_t f2bf(float f) {
  uint32_t u = __builtin_bit_cast(uint32_t, f);
  return (uint16_t)((u + 0x7FFFu + ((u >> 16) & 1u)) >> 16);
}

// truncating bf16x2 pack (P values; downward bias cancels in o/rs ratio).
__device__ __forceinline__ uint32_t pk2(float lo, float hi) {
  return (__builtin_bit_cast(uint32_t, hi) & 0xFFFF0000u) |
         (__builtin_bit_cast(uint32_t, lo) >> 16);
}

__device__ __forceinline__ void gload_lds16(const void* g, void* l) {
  __builtin_amdgcn_global_load_lds(
      (const __attribute__((address_space(1))) uint32_t*)(uintptr_t)g,
      (__attribute__((address_space(3))) uint32_t*)(uintptr_t)l, 16, 0, 0);
}

// ---------------- fused prep: 4 weight transposes + x convert, ONE launch ----------------
__global__ __launch_bounds__(256) void prep_kernel(const float* __restrict__ x,
                                                   const float* __restrict__ Wq,
                                                   const float* __restrict__ Wk,
                                                   const float* __restrict__ Wv,
                                                   const float* __restrict__ Wo,
                                                   uint16_t* __restrict__ xb,
                                                   uint16_t* __restrict__ Wt3,
                                                   uint16_t* __restrict__ Wot) {
  const int bid = blockIdx.x;
  if (bid < 4096) {
    __shared__ uint16_t tile[32][33];
    const int which = bid >> 10;
    const int tl = bid & 1023;
    const int bx = (tl & 31) * 32;  // n
    const int by = (tl >> 5) * 32;  // k
    const int tx = threadIdx.x & 31;
    const int ty = threadIdx.x >> 5;  // 0..7
    const float* W = (which == 0) ? Wq : (which == 1) ? Wk : (which == 2) ? Wv : Wo;
    uint16_t* Wt = (which < 3) ? (Wt3 + (size_t)which * (1u << 20)) : Wot;
#pragma unroll
    for (int j = 0; j < 4; j++)
      tile[ty + j * 8][tx] = f2bf(W[(size_t)(by + ty + j * 8) * 1024 + bx + tx]);
    __syncthreads();
#pragma unroll
    for (int j = 0; j < 4; j++)
      Wt[(size_t)(bx + ty + j * 8) * 1024 + by + tx] = tile[tx][ty + j * 8];
  } else {
    const int i = (bid - 4096) * 256 + threadIdx.x;  // i < 2M (= NB*NS*ND/4)
    const float4 f = *(const float4*)(x + (size_t)i * 4);
    union { uint16_t u[4]; uint64_t q; } o;
    o.u[0] = f2bf(f.x); o.u[1] = f2bf(f.y); o.u[2] = f2bf(f.z); o.u[3] = f2bf(f.w);
    *(uint64_t*)(xb + (size_t)i * 4) = o.q;
  }
}

// ---------------- GEMM: C[M][c] = A[M][K=1024] * Wt[c][K=1024]^T ----------------
// BK=64 double-buffered 2-phase, rotation-swizzled LDS, XCD-chunked supertile decode.
template <int MODE, int NBX>
__global__ __launch_bounds__(256) void gemm_bt(const uint16_t* __restrict__ A,
                                               const uint16_t* __restrict__ Bt,
                                               uint16_t* __restrict__ O0,
                                               uint16_t* __restrict__ O1,
                                               uint16_t* __restrict__ O2,
                                               float* __restrict__ OF) {
  __shared__ uint16_t lds[2][2][128 * 64];  // [buf][A/B][128 rows x 64 cols] = 64 KB
  const int tid = threadIdx.x;
  const int lane = tid & 63;
  const int wave = tid >> 6;
  const int wr = wave >> 1, wc = wave & 1;
  const int l15 = lane & 15, lg = lane >> 4;

  const int nwg = NBX * 64;
  const int wg = ((int)blockIdx.x & 7) * (nwg >> 3) + ((int)blockIdx.x >> 3);
  const int st = wg >> 5, in32 = wg & 31;
  const int sy = in32 >> 2, sx = in32 & 3;
  const int stx = st % (NBX / 4), sty = st / (NBX / 4);
  const int row0 = (sty * 8 + sy) * 128;
  const int col0 = (stx * 4 + sx) * 128;

  f32x4 acc[4][4];
#pragma unroll
  for (int i = 0; i < 4; i++)
#pragma unroll
    for (int j = 0; j < 4; j++) acc[i][j] = f32x4{0.f, 0.f, 0.f, 0.f};

  const char* Ag = (const char*)A + (size_t)row0 * 2048;
  const char* Bg = (const char*)Bt + (size_t)col0 * 2048;

  const int srr = tid >> 3;
  const int csrc = ((tid & 7) - srr) & 7;

#define STAGE_TILE(buf, t)                                                          \
  {                                                                                 \
    char* la = (char*)&lds[buf][0][0] + wave * 1024;                                \
    char* lb = (char*)&lds[buf][1][0] + wave * 1024;                                \
    _Pragma("unroll") for (int j = 0; j < 4; ++j) {                                 \
      const size_t off = (size_t)(j * 32 + srr) * 2048 + (size_t)(t) * 128 + csrc * 16; \
      gload_lds16(Ag + off, la + j * 4096);                                         \
      gload_lds16(Bg + off, lb + j * 4096);                                         \
    }                                                                               \
  }

  STAGE_TILE(0, 0);
  __syncthreads();

  int cur = 0;
  for (int t = 0; t < 16; ++t) {
    if (t < 15) STAGE_TILE(cur ^ 1, t + 1);
    const char* cA = (const char*)&lds[cur][0][0];
    const char* cB = (const char*)&lds[cur][1][0];
    bf16x8 af[4][2], bfr[4][2];
#pragma unroll
    for (int mi = 0; mi < 4; mi++) {
      const int row = wr * 64 + mi * 16 + l15;
#pragma unroll
      for (int ks = 0; ks < 2; ks++) {
        const int ch = (ks * 4 + lg + (l15 & 7)) & 7;
        af[mi][ks] = *(const bf16x8*)(cA + row * 128 + ch * 16);
      }
    }
#pragma unroll
    for (int ni = 0; ni < 4; ni++) {
      const int row = wc * 64 + ni * 16 + l15;
#pragma unroll
      for (int ks = 0; ks < 2; ks++) {
        const int ch = (ks * 4 + lg + (l15 & 7)) & 7;
        bfr[ni][ks] = *(const bf16x8*)(cB + row * 128 + ch * 16);
      }
    }
#pragma unroll
    for (int ks = 0; ks < 2; ks++)
#pragma unroll
      for (int mi = 0; mi < 4; mi++)
#pragma unroll
        for (int ni = 0; ni < 4; ni++)
          acc[mi][ni] = MFMA16(af[mi][ks], bfr[ni][ks], acc[mi][ni]);
    __syncthreads();
    cur ^= 1;
  }

#pragma unroll
  for (int mi = 0; mi < 4; mi++) {
#pragma unroll
    for (int ni = 0; ni < 4; ni++) {
      const int c = col0 + wc * 64 + ni * 16 + l15;
      const int rbase = row0 + wr * 64 + mi * 16 + lg * 4;
#pragma unroll
      for (int i = 0; i < 4; i++) {
        const int r = rbase + i;
        const float v = acc[mi][ni][i];
        if (MODE == 0) {
          const int which = c >> 10, cc = c & 1023;
          const int h = cc >> 6, dh = cc & 63;
          const int b = r >> 11, s = r & 2047;
          const size_t hb = (size_t)(b * NH + h);
          if (which == 0)
            O0[(hb * NS + s) * 64 + dh] = f2bf(v * 0.18033688011112042f);  // (1/8)*log2(e)
          else if (which == 1)
            O1[(hb * NS + s) * 64 + dh] = f2bf(v);
          else  // blocked V: [BH][t=s>>6][dh][s&63]
            O2[(((hb * 32 + (s >> 6)) * 64 + dh) * 64) + (s & 63)] = f2bf(v);
        } else {
          OF[(size_t)r * 1024 + c] = v;
        }
      }
    }
  }
#undef STAGE_TILE
}

// ---- stage one (K,V) tile pair (8KB each, contiguous) into wave-private LDS ----
__device__ __forceinline__ void stage_kv(const char* __restrict__ Kg,
                                         const char* __restrict__ Vg,
                                         char* kl, char* vl, int lane) {
#pragma unroll
  for (int j = 0; j < 8; ++j) {
    const int y = j * 1024 + lane * 16;
    const int r = y >> 7;
    const int zs = (r << 7) | ((((y >> 4) - r) & 7) << 4);
    gload_lds16(Kg + zs, kl + j * 1024);
    gload_lds16(Vg + zs, vl + j * 1024);
  }
}

// ---- one 32-row attention unit (round-19 structure + T5 setprio on PV cluster) ----
__device__ __forceinline__ void attn_unit(const uint16_t* __restrict__ Qh,
                                          const char* __restrict__ Kg,
                                          const char* __restrict__ Vg,
                                          uint16_t* __restrict__ Aout,
                                          int b, int h, int gp, int l15, int lg, int lane,
                                          char* kl, char* vl,
                                          uint16_t (*pX)[64][16]) {
  const int qbA = gp * 32;
  const int qbB = qbA + 16;
  const int tmax = gp >> 1;          // same last tile for both chains
  const int nfdA = (2 * gp) & 3;     // 0 or 2
  const int nfdB = nfdA + 1;

  stage_kv(Kg, Vg, kl, vl, lane);

  const bf16x8 qfA0 = *(const bf16x8*)&Qh[(size_t)(qbA + l15) * 64 + lg * 8];
  const bf16x8 qfA1 = *(const bf16x8*)&Qh[(size_t)(qbA + l15) * 64 + 32 + lg * 8];
  const bf16x8 qfB0 = *(const bf16x8*)&Qh[(size_t)(qbB + l15) * 64 + lg * 8];
  const bf16x8 qfB1 = *(const bf16x8*)&Qh[(size_t)(qbB + l15) * 64 + 32 + lg * 8];

  const short one_bf = (short)0x3F80;  // bf16 1.0
  const bf16x8 ones = {one_bf, one_bf, one_bf, one_bf, one_bf, one_bf, one_bf, one_bf};

  const int rsw = l15 & 7;

  const int wcol = ((lg + (l15 >> 2)) & 3) * 4;
  const int rr = l15 >> 2, cc0 = l15 & 3;
  const int rot = (2 * lg) & 3;
  const uint32_t pb = (uint32_t)(uintptr_t)&pX[0][0][0];
  const uint32_t addr0 = pb + (uint32_t)(lg * 256 + rr * 32 + (((cc0 + rot) & 3) * 8));
  const uint32_t addr1 = pb + (uint32_t)(lg * 256 + 128 + rr * 32 + (((cc0 + rot + 1) & 3) * 8));

  f32x4 oA[4], oB[4];
  f32x4 rsA = f32x4{0.f, 0.f, 0.f, 0.f};
  f32x4 rsB = f32x4{0.f, 0.f, 0.f, 0.f};
#pragma unroll
  for (int i = 0; i < 4; i++) {
    oA[i] = f32x4{0.f, 0.f, 0.f, 0.f};
    oB[i] = f32x4{0.f, 0.f, 0.f, 0.f};
  }

  for (int t = 0; t <= tmax; ++t) {
    asm volatile("s_waitcnt vmcnt(0)" ::: "memory");
    bf16x8 kf[4][2], vf[4][2];
#pragma unroll
    for (int nf = 0; nf < 4; ++nf)
#pragma unroll
      for (int kk = 0; kk < 2; ++kk) {
        const int off = (nf * 16 + l15) * 128 + (((kk * 4 + lg) + rsw) & 7) * 16;
        kf[nf][kk] = *(const bf16x8*)(kl + off);
        vf[nf][kk] = *(const bf16x8*)(vl + off);
      }
    asm volatile("s_waitcnt lgkmcnt(0)" ::: "memory");
    if (t < tmax) stage_kv(Kg + (size_t)(t + 1) * 8192, Vg + (size_t)(t + 1) * 8192, kl, vl, lane);

    const int nfmA = (t == tmax) ? nfdA : 3;
    const int nfmB = (t == tmax) ? nfdB : 3;
#pragma unroll
    for (int nf = 0; nf < 4; ++nf) {
      if (nf <= nfmB) {
        f32x4 a = f32x4{0.f, 0.f, 0.f, 0.f};
        a = MFMA16(qfB0, kf[nf][0], a);
        a = MFMA16(qfB1, kf[nf][1], a);
        if (t == tmax && nf == nfdB) {
#pragma unroll
          for (int i = 0; i < 4; i++)
            if (l15 > lg * 4 + i) a[i] = -1e30f;
        }
        {
          const float e0 = exp2f(a[0]), e1 = exp2f(a[1]);
          const float e2 = exp2f(a[2]), e3 = exp2f(a[3]);
          *(uint64_t*)&pX[1][nf * 16 + l15][wcol] =
              ((uint64_t)pk2(e2, e3) << 32) | pk2(e0, e1);
        }
        if (nf <= nfmA) {
          f32x4 c = f32x4{0.f, 0.f, 0.f, 0.f};
          c = MFMA16(qfA0, kf[nf][0], c);
          c = MFMA16(qfA1, kf[nf][1], c);
          if (t == tmax && nf == nfdA) {
#pragma unroll
            for (int i = 0; i < 4; i++)
              if (l15 > lg * 4 + i) c[i] = -1e30f;
          }
          const float e0 = exp2f(c[0]), e1 = exp2f(c[1]);
          const float e2 = exp2f(c[2]), e3 = exp2f(c[3]);
          *(uint64_t*)&pX[0][nf * 16 + l15][wcol] =
              ((uint64_t)pk2(e2, e3) << 32) | pk2(e0, e1);
        } else {
          *(uint64_t*)&pX[0][nf * 16 + l15][wcol] = 0ull;
        }
      } else {
        *(uint64_t*)&pX[0][nf * 16 + l15][wcol] = 0ull;
        *(uint64_t*)&pX[1][nf * 16 + l15][wcol] = 0ull;
      }
    }
    u32x2 a0, a1, a2, a3, b0, b1, b2, b3;
    asm volatile(
        "ds_read_b64_tr_b16 %0, %8\n\t"
        "ds_read_b64_tr_b16 %1, %9\n\t"
        "ds_read_b64_tr_b16 %2, %8 offset:1024\n\t"
        "ds_read_b64_tr_b16 %3, %9 offset:1024\n\t"
        "ds_read_b64_tr_b16 %4, %8 offset:2048\n\t"
        "ds_read_b64_tr_b16 %5, %9 offset:2048\n\t"
        "ds_read_b64_tr_b16 %6, %8 offset:3072\n\t"
        "ds_read_b64_tr_b16 %7, %9 offset:3072\n\t"
        "s_waitcnt lgkmcnt(0)"
        : "=&v"(a0), "=&v"(a1), "=&v"(a2), "=&v"(a3),
          "=&v"(b0), "=&v"(b1), "=&v"(b2), "=&v"(b3)
        : "v"(addr0), "v"(addr1)
        : "memory");
    union { u32x2 u2[2]; bf16x8 v8; } uA0, uA1, uB0, uB1;
    uA0.u2[0] = a0; uA0.u2[1] = a1;
    uA1.u2[0] = a2; uA1.u2[1] = a3;
    uB0.u2[0] = b0; uB0.u2[1] = b1;
    uB1.u2[0] = b2; uB1.u2[1] = b3;
    const bf16x8 paA0 = uA0.v8, paA1 = uA1.v8;
    const bf16x8 paB0 = uB0.v8, paB1 = uB1.v8;
    __builtin_amdgcn_s_setprio(1);
    rsA = MFMA16(paA0, ones, rsA);
    rsA = MFMA16(paA1, ones, rsA);
    rsB = MFMA16(paB0, ones, rsB);
    rsB = MFMA16(paB1, ones, rsB);
#pragma unroll
    for (int df = 0; df < 4; ++df) {
      oA[df] = MFMA16(paA0, vf[df][0], oA[df]);
      oA[df] = MFMA16(paA1, vf[df][1], oA[df]);
      oB[df] = MFMA16(paB0, vf[df][0], oB[df]);
      oB[df] = MFMA16(paB1, vf[df][1], oB[df]);
    }
    __builtin_amdgcn_s_setprio(0);
  }

#pragma unroll
  for (int df = 0; df < 4; ++df) {
#pragma unroll
    for (int i = 0; i < 4; i++) {
      const int qA = qbA + lg * 4 + i;
      const int qB = qbB + lg * 4 + i;
      Aout[((size_t)(b * NS + qA)) * 1024 + h * 64 + df * 16 + l15] = f2bf(oA[df][i] / rsA[i]);
      Aout[((size_t)(b * NS + qB)) * 1024 + h * 64 + df * 16 + l15] = f2bf(oB[df][i] / rsB[i]);
    }
  }
}

// ---------------- causal flash attention (wave = two sequential balanced units) ----------------
__global__ __launch_bounds__(256) void attn_fwd(const uint16_t* __restrict__ Q,
                                                const uint16_t* __restrict__ K,
                                                const uint16_t* __restrict__ Vt,
                                                uint16_t* __restrict__ Aout) {
  const int bid = blockIdx.x;
  const int xcd = bid & 7;
  const int sp = (bid >> 3) & 3;
  const int gblk = bid >> 5;  // 0..15

  const int w = threadIdx.x >> 6;
  const int lane = threadIdx.x & 63;
  const int l15 = lane & 15, lg = lane >> 4;
  const int g = gblk * 4 + w;  // 0..63

  __shared__ __align__(16) uint16_t plds[4][2][64][16];  // P buffers (16 KB)
  __shared__ __align__(16) char kstage[4][8192];         // K tiles  (32 KB)
  __shared__ __align__(16) char vstage[4][8192];         // V tiles  (32 KB)

  for (int seg = 0; seg < 2; ++seg) {
    const int slot = sp * 2 + seg;
    const int bh = (slot << 3) | xcd;
    const int gp = seg ? (63 - g) : g;
    const uint16_t* Qh = Q + (size_t)bh * (NS * 64);
    const char* Kg = (const char*)(K + (size_t)bh * (NS * 64));
    const char* Vg = (const char*)(Vt + (size_t)bh * (32 * 64 * 64));
    attn_unit(Qh, Kg, Vg, Aout, bh >> 4, bh & 15, gp, l15, lg, lane,
              kstage[w], vstage[w], plds[w]);
  }
}

extern "C" void kernel_launch(void* const* d_in, const int* in_sizes, int n_in,
                              void* d_out, int out_size, void* d_ws, size_t ws_size,
                              hipStream_t stream) {
  const float* x = (const float*)d_in[0];
  const float* Wq = (const float*)d_in[1];
  const float* Wk = (const float*)d_in[2];
  const float* Wv = (const float*)d_in[3];
  const float* Wo = (const float*)d_in[4];
  float* out = (float*)d_out;

  char* ws = (char*)d_ws;
  uint16_t* xb = (uint16_t*)(ws);                        // 16 MB  (reused as attn buffer)
  uint16_t* Wt3 = (uint16_t*)(ws + (16u << 20));         // 6 MB   [3][1024][1024] (n-major)
  uint16_t* Wot = (uint16_t*)(ws + (22u << 20));         // 2 MB
  uint16_t* Qb = (uint16_t*)(ws + (24u << 20));          // 16 MB  [BH][S][64]
  uint16_t* Kb = (uint16_t*)(ws + (40u << 20));          // 16 MB  [BH][S][64]
  uint16_t* Vt = (uint16_t*)(ws + (56u << 20));          // 16 MB  blocked [BH][32][64][64]
  uint16_t* attn = xb;                                   // total 72 MB

  prep_kernel<<<12288, 256, 0, stream>>>(x, Wq, Wk, Wv, Wo, xb, Wt3, Wot);

  gemm_bt<0, 24><<<1536, 256, 0, stream>>>(xb, Wt3, Qb, Kb, Vt, nullptr);
  attn_fwd<<<512, 256, 0, stream>>>(Qb, Kb, Vt, attn);
  gemm_bt<1, 8><<<512, 256, 0, stream>>>(attn, Wot, nullptr, nullptr, nullptr, out);
}